// Round 1
// baseline (652.998 us; speedup 1.0000x reference)
//
#include <hip/hip_runtime.h>

// ---------------- graph preprocessing kernels ----------------

__global__ __launch_bounds__(256) void zero_int_kernel(int* __restrict__ p, int n) {
    int i = blockIdx.x * blockDim.x + threadIdx.x;
    if (i < n) p[i] = 0;
}

__global__ __launch_bounds__(256) void count_edges_kernel(const int* __restrict__ dst, int E,
                                                          int* __restrict__ cnt) {
    int e = blockIdx.x * blockDim.x + threadIdx.x;
    if (e < E) atomicAdd(&cnt[dst[e]], 1);
}

__global__ __launch_bounds__(256) void dinv_kernel(const int* __restrict__ cnt,
                                                   float* __restrict__ dinv, int n) {
    int i = blockIdx.x * blockDim.x + threadIdx.x;
    if (i < n) dinv[i] = rsqrtf((float)(cnt[i] + 1));   // +1 self-loop
}

// single-block exclusive scan over n counts -> row[0..n]
__global__ __launch_bounds__(1024) void scan_rowptr_kernel(const int* __restrict__ cnt,
                                                           int* __restrict__ row, int n) {
    __shared__ int part[1024];
    int tid = threadIdx.x;
    int chunk = (n + 1023) >> 10;
    int begin = tid * chunk;
    int end = begin + chunk; if (end > n) end = n;
    int s = 0;
    for (int i = begin; i < end && begin < n; ++i) s += cnt[i];
    part[tid] = s;
    __syncthreads();
    for (int off = 1; off < 1024; off <<= 1) {
        int u = (tid >= off) ? part[tid - off] : 0;
        __syncthreads();
        part[tid] += u;
        __syncthreads();
    }
    int run = (tid > 0) ? part[tid - 1] : 0;
    if (begin < n) {
        for (int i = begin; i < end; ++i) { row[i] = run; run += cnt[i]; }
        if (end == n) row[n] = run;
    }
}

__global__ __launch_bounds__(256) void init_cursor_kernel(const int* __restrict__ row,
                                                          int* __restrict__ cur, int n) {
    int i = blockIdx.x * blockDim.x + threadIdx.x;
    if (i < n) cur[i] = row[i];
}

__global__ __launch_bounds__(256) void scatter_edges_kernel(const int* __restrict__ src,
                                                            const int* __restrict__ dst, int E,
                                                            int* __restrict__ cur,
                                                            int* __restrict__ csr_src) {
    int e = blockIdx.x * blockDim.x + threadIdx.x;
    if (e < E) {
        int d = dst[e];
        int pos = atomicAdd(&cur[d], 1);
        csr_src[pos] = src[e];
    }
}

// ---------------- per-layer kernels ----------------

// H[r][c] = (sum_k X[r][k] * W[k][c]) * dinv[r]
template <int IN, int OUT, int ROWS>
__global__ __launch_bounds__(256) void gemm_scale_kernel(const float* __restrict__ X,
                                                         const float* __restrict__ W,
                                                         const float* __restrict__ dinv,
                                                         float* __restrict__ H, int n) {
    __shared__ float Wl[IN * OUT];
    int tid = threadIdx.x;                      // blockDim.x == OUT*ROWS == 256
    for (int i = tid; i < IN * OUT; i += OUT * ROWS) Wl[i] = W[i];
    __syncthreads();
    int c = tid % OUT;
    int r = blockIdx.x * ROWS + tid / OUT;
    if (r >= n) return;
    const float* xr = X + (size_t)r * IN;
    float acc = 0.f;
#pragma unroll
    for (int k = 0; k < IN; k += 4) {
        float4 xv = *reinterpret_cast<const float4*>(xr + k);
        acc = fmaf(xv.x, Wl[(k + 0) * OUT + c], acc);
        acc = fmaf(xv.y, Wl[(k + 1) * OUT + c], acc);
        acc = fmaf(xv.z, Wl[(k + 2) * OUT + c], acc);
        acc = fmaf(xv.w, Wl[(k + 3) * OUT + c], acc);
    }
    H[(size_t)r * OUT + c] = acc * dinv[r];
}

// out[d][c] = dinv[d] * (H'[d][c] + sum_{s in in(d)} H'[s][c]) + b[c]   (+ optional relu)
template <int C, bool RELU>
__global__ __launch_bounds__(256) void aggregate_kernel(const float* __restrict__ H,
                                                        const int* __restrict__ row,
                                                        const int* __restrict__ csr_src,
                                                        const float* __restrict__ dinv,
                                                        const float* __restrict__ bias,
                                                        float* __restrict__ Y, int n) {
    constexpr int SUB = (C <= 64) ? (64 / C) : 1;   // nodes per wave
    constexpr int VEC = (C + 63) / 64;              // channels per lane (1 or 2)
    int wid = (blockIdx.x * blockDim.x + threadIdx.x) >> 6;
    int lane = threadIdx.x & 63;
    int node = wid * SUB + (SUB > 1 ? lane / C : 0);
    if (node >= n) return;
    int c0 = (SUB > 1) ? (lane % C) : lane * VEC;

    float acc[VEC];
    {
        const float* hr = H + (size_t)node * C + c0;
#pragma unroll
        for (int v = 0; v < VEC; ++v) acc[v] = hr[v];   // self-loop
    }
    int e = row[node], end = row[node + 1];
    for (; e < end; ++e) {
        int s = csr_src[e];
        const float* hs = H + (size_t)s * C + c0;
#pragma unroll
        for (int v = 0; v < VEC; ++v) acc[v] += hs[v];
    }
    float dv = dinv[node];
#pragma unroll
    for (int v = 0; v < VEC; ++v) {
        float o = fmaf(acc[v], dv, bias[c0 + v]);
        if (RELU) o = fmaxf(o, 0.f);
        Y[(size_t)node * C + c0 + v] = o;
    }
}

// ---------------- host launch ----------------

static inline int cdiv(int a, int b) { return (a + b - 1) / b; }

extern "C" void kernel_launch(void* const* d_in, const int* in_sizes, int n_in,
                              void* d_out, int out_size, void* d_ws, size_t ws_size,
                              hipStream_t stream) {
    const float* x   = (const float*)d_in[0];
    const int*   ei  = (const int*)d_in[1];
    const float* We1 = (const float*)d_in[2];
    const float* be1 = (const float*)d_in[3];
    const float* We2 = (const float*)d_in[4];
    const float* be2 = (const float*)d_in[5];
    const float* Wd1 = (const float*)d_in[6];
    const float* bd1 = (const float*)d_in[7];
    const float* Wd2 = (const float*)d_in[8];
    const float* bd2 = (const float*)d_in[9];

    const int n = in_sizes[0] / 128;
    const int E = in_sizes[1] / 2;
    const int* src = ei;
    const int* dst = ei + E;

    // carve workspace (256B aligned)
    char* ws = (char*)d_ws;
    auto carve = [&](size_t bytes) -> void* {
        void* p = (void*)ws;
        ws += (bytes + 255) & ~(size_t)255;
        return p;
    };
    int*   cnt  = (int*)carve((size_t)n * 4);
    int*   rowp = (int*)carve((size_t)(n + 1) * 4);
    int*   cur  = (int*)carve((size_t)n * 4);
    int*   csr  = (int*)carve((size_t)E * 4);
    float* dinv = (float*)carve((size_t)n * 4);
    float* bufA = (float*)carve((size_t)n * 128 * 4);
    float* bufB = (float*)carve((size_t)n * 64 * 4);
    float* bufC = (float*)carve((size_t)n * 32 * 4);

    // ---- graph preprocessing ----
    zero_int_kernel<<<cdiv(n, 256), 256, 0, stream>>>(cnt, n);
    count_edges_kernel<<<cdiv(E, 256), 256, 0, stream>>>(dst, E, cnt);
    dinv_kernel<<<cdiv(n, 256), 256, 0, stream>>>(cnt, dinv, n);
    scan_rowptr_kernel<<<1, 1024, 0, stream>>>(cnt, rowp, n);
    init_cursor_kernel<<<cdiv(n, 256), 256, 0, stream>>>(rowp, cur, n);
    scatter_edges_kernel<<<cdiv(E, 256), 256, 0, stream>>>(src, dst, E, cur, csr);

    // ---- layer 1: in=128 -> out=64, relu ----
    gemm_scale_kernel<128, 64, 4><<<cdiv(n, 4), 256, 0, stream>>>(x, We1, dinv, bufA, n);
    aggregate_kernel<64, true><<<cdiv(n * 64, 256), 256, 0, stream>>>(bufA, rowp, csr, dinv, be1, bufB, n);

    // ---- layer 2: 64 -> 32 ----
    gemm_scale_kernel<64, 32, 8><<<cdiv(n, 8), 256, 0, stream>>>(bufB, We2, dinv, bufA, n);
    aggregate_kernel<32, false><<<cdiv(n * 32, 256), 256, 0, stream>>>(bufA, rowp, csr, dinv, be2, bufC, n);

    // ---- layer 3: 32 -> 64, relu ----
    gemm_scale_kernel<32, 64, 4><<<cdiv(n, 4), 256, 0, stream>>>(bufC, Wd1, dinv, bufA, n);
    aggregate_kernel<64, true><<<cdiv(n * 64, 256), 256, 0, stream>>>(bufA, rowp, csr, dinv, bd1, bufB, n);

    // ---- layer 4: 64 -> 128 ----
    gemm_scale_kernel<64, 128, 2><<<cdiv(n, 2), 256, 0, stream>>>(bufB, Wd2, dinv, bufA, n);
    aggregate_kernel<128, false><<<cdiv(n * 64, 256), 256, 0, stream>>>(bufA, rowp, csr, dinv, bd2, (float*)d_out, n);
}

// Round 2
// 437.540 us; speedup vs baseline: 1.4924x; 1.4924x over previous
//
#include <hip/hip_runtime.h>

// ---------------- graph preprocessing kernels ----------------

__global__ __launch_bounds__(256) void zero_int_kernel(int* __restrict__ p, int n) {
    int i = blockIdx.x * blockDim.x + threadIdx.x;
    if (i < n) p[i] = 0;
}

__global__ __launch_bounds__(256) void count_edges_kernel(const int* __restrict__ dst, int E,
                                                          int* __restrict__ cnt) {
    int e = blockIdx.x * blockDim.x + threadIdx.x;
    if (e < E) atomicAdd(&cnt[dst[e]], 1);
}

static constexpr int SCAN_CHUNK = 2048;   // per block: 256 threads x 8 elements

// per-block sum of cnt (+ dinv computed on the fly)
__global__ __launch_bounds__(256) void block_sum_kernel(const int* __restrict__ cnt, int n,
                                                        int* __restrict__ bsum,
                                                        float* __restrict__ dinv) {
    int tid = threadIdx.x;
    int base = blockIdx.x * SCAN_CHUNK;
    int lim = base + SCAN_CHUNK; if (lim > n) lim = n;
    int s = 0;
    for (int i = base + tid; i < lim; i += 256) {      // coalesced
        int c = cnt[i];
        s += c;
        dinv[i] = rsqrtf((float)(c + 1));              // +1 self-loop
    }
    __shared__ int red[4];
#pragma unroll
    for (int m = 1; m < 64; m <<= 1) s += __shfl_xor(s, m);
    int lane = tid & 63, w = tid >> 6;
    if (lane == 0) red[w] = s;
    __syncthreads();
    if (tid == 0) bsum[blockIdx.x] = red[0] + red[1] + red[2] + red[3];
}

// per-block exclusive scan with global offset; writes rowp and cur
__global__ __launch_bounds__(256) void local_scan_kernel(const int* __restrict__ cnt, int n,
                                                         const int* __restrict__ bsum,
                                                         int* __restrict__ rowp,
                                                         int* __restrict__ cur) {
    __shared__ int soff;
    __shared__ int wsum[4];
    int tid = threadIdx.x;
    int b = blockIdx.x;
    int lane = tid & 63, w = tid >> 6;
    if (tid < 64) {
        int v = 0;
        for (int i = tid; i < b; i += 64) v += bsum[i];
#pragma unroll
        for (int m = 1; m < 64; m <<= 1) v += __shfl_xor(v, m);
        if (tid == 0) soff = v;
    }
    int base = b * SCAN_CHUNK + tid * 8;
    int vals[8];
    int s = 0;
#pragma unroll
    for (int k = 0; k < 8; ++k) {
        int i = base + k;
        int c = (i < n) ? cnt[i] : 0;
        vals[k] = c;
        s += c;
    }
    // wave inclusive scan of s
    int inc = s;
#pragma unroll
    for (int m = 1; m < 64; m <<= 1) {
        int u = __shfl_up(inc, m);
        if (lane >= m) inc += u;
    }
    if (lane == 63) wsum[w] = inc;
    __syncthreads();
    int off = soff;
    for (int i = 0; i < w; ++i) off += wsum[i];
    int run = off + inc - s;                 // exclusive prefix for this thread's 8 elems
#pragma unroll
    for (int k = 0; k < 8; ++k) {
        int i = base + k;
        if (i < n) { rowp[i] = run; cur[i] = run; }
        run += vals[k];
    }
    if (b == (int)gridDim.x - 1 && tid == 255) rowp[n] = run;  // == E
}

__global__ __launch_bounds__(256) void scatter_edges_kernel(const int* __restrict__ src,
                                                            const int* __restrict__ dst, int E,
                                                            int* __restrict__ cur,
                                                            int* __restrict__ csr_src) {
    int e = blockIdx.x * blockDim.x + threadIdx.x;
    if (e < E) {
        int d = dst[e];
        int pos = atomicAdd(&cur[d], 1);
        csr_src[pos] = src[e];
    }
}

// ---------------- per-layer kernels ----------------

// H[r][c] = (sum_k X[r][k] * W[k][c]) * dinv[r]
template <int IN, int OUT, int ROWS>
__global__ __launch_bounds__(256) void gemm_scale_kernel(const float* __restrict__ X,
                                                         const float* __restrict__ W,
                                                         const float* __restrict__ dinv,
                                                         float* __restrict__ H, int n) {
    __shared__ float Wl[IN * OUT];
    int tid = threadIdx.x;                      // blockDim.x == OUT*ROWS == 256
    for (int i = tid; i < IN * OUT; i += OUT * ROWS) Wl[i] = W[i];
    __syncthreads();
    int c = tid % OUT;
    int r = blockIdx.x * ROWS + tid / OUT;
    if (r >= n) return;
    const float* xr = X + (size_t)r * IN;
    float acc = 0.f;
#pragma unroll
    for (int k = 0; k < IN; k += 4) {
        float4 xv = *reinterpret_cast<const float4*>(xr + k);
        acc = fmaf(xv.x, Wl[(k + 0) * OUT + c], acc);
        acc = fmaf(xv.y, Wl[(k + 1) * OUT + c], acc);
        acc = fmaf(xv.z, Wl[(k + 2) * OUT + c], acc);
        acc = fmaf(xv.w, Wl[(k + 3) * OUT + c], acc);
    }
    H[(size_t)r * OUT + c] = acc * dinv[r];
}

// One wave per node. Lanes split into EG = 64/(C/4) edge groups; each lane loads
// float4 of channels. Cross-group shfl_xor reduce at the end.
// out[d][:] = dinv[d] * (H[d][:] + sum_{s in in(d)} H[s][:]) + b[:]  (+ optional relu)
template <int C, bool RELU>
__global__ __launch_bounds__(256) void aggregate_kernel(const float* __restrict__ H,
                                                        const int* __restrict__ row,
                                                        const int* __restrict__ csr_src,
                                                        const float* __restrict__ dinv,
                                                        const float* __restrict__ bias,
                                                        float* __restrict__ Y, int n) {
    constexpr int LPN = C / 4;        // lanes covering one row: 8 / 16 / 32
    constexpr int EG = 64 / LPN;      // edge groups: 8 / 4 / 2
    int wid = (blockIdx.x * blockDim.x + threadIdx.x) >> 6;
    if (wid >= n) return;             // wave-uniform exit
    int lane = threadIdx.x & 63;
    int g = lane / LPN;
    int c0 = (lane % LPN) * 4;
    const int node = wid;

    float4 acc = make_float4(0.f, 0.f, 0.f, 0.f);
    if (g == 0) acc = *reinterpret_cast<const float4*>(H + (size_t)node * C + c0);  // self-loop
    int end = row[node + 1];
    for (int e = row[node] + g; e < end; e += EG) {
        int s = csr_src[e];
        float4 hv = *reinterpret_cast<const float4*>(H + (size_t)s * C + c0);
        acc.x += hv.x; acc.y += hv.y; acc.z += hv.z; acc.w += hv.w;
    }
#pragma unroll
    for (int m = LPN; m < 64; m <<= 1) {
        acc.x += __shfl_xor(acc.x, m);
        acc.y += __shfl_xor(acc.y, m);
        acc.z += __shfl_xor(acc.z, m);
        acc.w += __shfl_xor(acc.w, m);
    }
    if (g == 0) {
        float dv = dinv[node];
        float4 o;
        o.x = fmaf(acc.x, dv, bias[c0 + 0]);
        o.y = fmaf(acc.y, dv, bias[c0 + 1]);
        o.z = fmaf(acc.z, dv, bias[c0 + 2]);
        o.w = fmaf(acc.w, dv, bias[c0 + 3]);
        if (RELU) {
            o.x = fmaxf(o.x, 0.f); o.y = fmaxf(o.y, 0.f);
            o.z = fmaxf(o.z, 0.f); o.w = fmaxf(o.w, 0.f);
        }
        *reinterpret_cast<float4*>(Y + (size_t)node * C + c0) = o;
    }
}

// ---------------- host launch ----------------

static inline int cdiv(int a, int b) { return (a + b - 1) / b; }

extern "C" void kernel_launch(void* const* d_in, const int* in_sizes, int n_in,
                              void* d_out, int out_size, void* d_ws, size_t ws_size,
                              hipStream_t stream) {
    const float* x   = (const float*)d_in[0];
    const int*   ei  = (const int*)d_in[1];
    const float* We1 = (const float*)d_in[2];
    const float* be1 = (const float*)d_in[3];
    const float* We2 = (const float*)d_in[4];
    const float* be2 = (const float*)d_in[5];
    const float* Wd1 = (const float*)d_in[6];
    const float* bd1 = (const float*)d_in[7];
    const float* Wd2 = (const float*)d_in[8];
    const float* bd2 = (const float*)d_in[9];

    const int n = in_sizes[0] / 128;
    const int E = in_sizes[1] / 2;
    const int* src = ei;
    const int* dst = ei + E;
    const int nb = cdiv(n, SCAN_CHUNK);

    // carve workspace (256B aligned)
    char* ws = (char*)d_ws;
    auto carve = [&](size_t bytes) -> void* {
        void* p = (void*)ws;
        ws += (bytes + 255) & ~(size_t)255;
        return p;
    };
    int*   cnt  = (int*)carve((size_t)n * 4);
    int*   rowp = (int*)carve((size_t)(n + 1) * 4);
    int*   cur  = (int*)carve((size_t)n * 4);
    int*   csr  = (int*)carve((size_t)E * 4);
    float* dinv = (float*)carve((size_t)n * 4);
    int*   bsum = (int*)carve((size_t)nb * 4);
    float* bufA = (float*)carve((size_t)n * 128 * 4);
    float* bufB = (float*)carve((size_t)n * 64 * 4);
    float* bufC = (float*)carve((size_t)n * 32 * 4);

    // ---- graph preprocessing ----
    zero_int_kernel<<<cdiv(n, 256), 256, 0, stream>>>(cnt, n);
    count_edges_kernel<<<cdiv(E, 256), 256, 0, stream>>>(dst, E, cnt);
    block_sum_kernel<<<nb, 256, 0, stream>>>(cnt, n, bsum, dinv);
    local_scan_kernel<<<nb, 256, 0, stream>>>(cnt, n, bsum, rowp, cur);
    scatter_edges_kernel<<<cdiv(E, 256), 256, 0, stream>>>(src, dst, E, cur, csr);

    // ---- layer 1: in=128 -> out=64, relu ----
    gemm_scale_kernel<128, 64, 4><<<cdiv(n, 4), 256, 0, stream>>>(x, We1, dinv, bufA, n);
    aggregate_kernel<64, true><<<cdiv(n * 64, 256), 256, 0, stream>>>(bufA, rowp, csr, dinv, be1, bufB, n);

    // ---- layer 2: 64 -> 32 ----
    gemm_scale_kernel<64, 32, 8><<<cdiv(n, 8), 256, 0, stream>>>(bufB, We2, dinv, bufA, n);
    aggregate_kernel<32, false><<<cdiv(n * 64, 256), 256, 0, stream>>>(bufA, rowp, csr, dinv, be2, bufC, n);

    // ---- layer 3: 32 -> 64, relu ----
    gemm_scale_kernel<32, 64, 4><<<cdiv(n, 4), 256, 0, stream>>>(bufC, Wd1, dinv, bufA, n);
    aggregate_kernel<64, true><<<cdiv(n * 64, 256), 256, 0, stream>>>(bufA, rowp, csr, dinv, bd1, bufB, n);

    // ---- layer 4: 64 -> 128 ----
    gemm_scale_kernel<64, 128, 2><<<cdiv(n, 2), 256, 0, stream>>>(bufB, Wd2, dinv, bufA, n);
    aggregate_kernel<128, false><<<cdiv(n * 64, 256), 256, 0, stream>>>(bufA, rowp, csr, dinv, bd2, (float*)d_out, n);
}

// Round 3
// 314.900 us; speedup vs baseline: 2.0737x; 1.3895x over previous
//
#include <hip/hip_runtime.h>

// ---------------- graph preprocessing kernels ----------------

__global__ __launch_bounds__(256) void zero_int_kernel(int* __restrict__ p, int n) {
    int i = blockIdx.x * blockDim.x + threadIdx.x;
    if (i < n) p[i] = 0;
}

__global__ __launch_bounds__(256) void count_edges_kernel(const int* __restrict__ dst, int E,
                                                          int* __restrict__ cnt) {
    int e = blockIdx.x * blockDim.x + threadIdx.x;
    if (e < E) atomicAdd(&cnt[dst[e]], 1);
}

static constexpr int SCAN_CHUNK = 2048;   // per block: 256 threads x 8 elements

// per-block sum of cnt (+ dinv computed on the fly)
__global__ __launch_bounds__(256) void block_sum_kernel(const int* __restrict__ cnt, int n,
                                                        int* __restrict__ bsum,
                                                        float* __restrict__ dinv) {
    int tid = threadIdx.x;
    int base = blockIdx.x * SCAN_CHUNK;
    int lim = base + SCAN_CHUNK; if (lim > n) lim = n;
    int s = 0;
    for (int i = base + tid; i < lim; i += 256) {      // coalesced
        int c = cnt[i];
        s += c;
        dinv[i] = rsqrtf((float)(c + 1));              // +1 self-loop
    }
    __shared__ int red[4];
#pragma unroll
    for (int m = 1; m < 64; m <<= 1) s += __shfl_xor(s, m);
    int lane = tid & 63, w = tid >> 6;
    if (lane == 0) red[w] = s;
    __syncthreads();
    if (tid == 0) bsum[blockIdx.x] = red[0] + red[1] + red[2] + red[3];
}

// per-block exclusive scan with global offset; writes rowp and cur
__global__ __launch_bounds__(256) void local_scan_kernel(const int* __restrict__ cnt, int n,
                                                         const int* __restrict__ bsum,
                                                         int* __restrict__ rowp,
                                                         int* __restrict__ cur) {
    __shared__ int soff;
    __shared__ int wsum[4];
    int tid = threadIdx.x;
    int b = blockIdx.x;
    int lane = tid & 63, w = tid >> 6;
    if (tid < 64) {
        int v = 0;
        for (int i = tid; i < b; i += 64) v += bsum[i];
#pragma unroll
        for (int m = 1; m < 64; m <<= 1) v += __shfl_xor(v, m);
        if (tid == 0) soff = v;
    }
    int base = b * SCAN_CHUNK + tid * 8;
    int vals[8];
    int s = 0;
#pragma unroll
    for (int k = 0; k < 8; ++k) {
        int i = base + k;
        int c = (i < n) ? cnt[i] : 0;
        vals[k] = c;
        s += c;
    }
    // wave inclusive scan of s
    int inc = s;
#pragma unroll
    for (int m = 1; m < 64; m <<= 1) {
        int u = __shfl_up(inc, m);
        if (lane >= m) inc += u;
    }
    if (lane == 63) wsum[w] = inc;
    __syncthreads();
    int off = soff;
    for (int i = 0; i < w; ++i) off += wsum[i];
    int run = off + inc - s;                 // exclusive prefix for this thread's 8 elems
#pragma unroll
    for (int k = 0; k < 8; ++k) {
        int i = base + k;
        if (i < n) { rowp[i] = run; cur[i] = run; }
        run += vals[k];
    }
    if (b == (int)gridDim.x - 1 && tid == 255) rowp[n] = run;  // == E
}

__global__ __launch_bounds__(256) void scatter_edges_kernel(const int* __restrict__ src,
                                                            const int* __restrict__ dst, int E,
                                                            int* __restrict__ cur,
                                                            int* __restrict__ csr_src) {
    int e = blockIdx.x * blockDim.x + threadIdx.x;
    if (e < E) {
        int d = dst[e];
        int pos = atomicAdd(&cur[d], 1);
        csr_src[pos] = src[e];
    }
}

// ---------------- per-layer kernels ----------------

// Block-tiled GEMM + dinv row-scale: H[r][co+c] = (sum_k X[r][k] W[k][co+c]) * dinv[r]
// Block tile: 64 rows x BN cols. Thread tile: 4x4. A staged transposed in LDS
// (At[k][r], row stride 68 to avoid bank conflicts), B panel fully LDS-resident.
template <int K, int OUT, int BN>
__global__ __launch_bounds__(16 * (BN / 4)) void gemm_tile_kernel(
        const float* __restrict__ X, const float* __restrict__ W,
        const float* __restrict__ dinv, float* __restrict__ H, int n) {
    constexpr int BM = 64;
    constexpr int KB = (K > 64) ? 64 : K;
    constexpr int NTHR = 16 * (BN / 4);
    constexpr int KV = KB / 4;              // float4s per A row chunk

    __shared__ float At[KB][BM + 4];        // [k][r], stride 68 floats
    __shared__ float Bl[K][BN];

    const int tid = threadIdx.x;
    const int tx = tid % (BN / 4);
    const int ty = tid / (BN / 4);
    const int rb = blockIdx.x * BM;
    const int co = blockIdx.y * BN;

    // load B panel (W[:, co:co+BN]) once
    for (int i = tid; i < K * BN / 4; i += NTHR) {
        int k = i / (BN / 4);
        int c0 = (i % (BN / 4)) * 4;
        *reinterpret_cast<float4*>(&Bl[k][c0]) =
            *reinterpret_cast<const float4*>(&W[(size_t)k * OUT + co + c0]);
    }

    float acc[4][4] = {};

#pragma unroll
    for (int ch = 0; ch < K / KB; ++ch) {
        if (ch) __syncthreads();            // previous chunk's readers done
        // stage A chunk transposed
        for (int i = tid; i < BM * KV; i += NTHR) {
            int r = i / KV;
            int k0 = (i % KV) * 4;
            int rg = rb + r; if (rg > n - 1) rg = n - 1;     // clamp tail
            float4 xv = *reinterpret_cast<const float4*>(&X[(size_t)rg * K + ch * KB + k0]);
            At[k0 + 0][r] = xv.x;
            At[k0 + 1][r] = xv.y;
            At[k0 + 2][r] = xv.z;
            At[k0 + 3][r] = xv.w;
        }
        __syncthreads();

#pragma unroll 8
        for (int k = 0; k < KB; ++k) {
            float4 a = *reinterpret_cast<const float4*>(&At[k][ty * 4]);
            float4 b = *reinterpret_cast<const float4*>(&Bl[ch * KB + k][tx * 4]);
            acc[0][0] = fmaf(a.x, b.x, acc[0][0]); acc[0][1] = fmaf(a.x, b.y, acc[0][1]);
            acc[0][2] = fmaf(a.x, b.z, acc[0][2]); acc[0][3] = fmaf(a.x, b.w, acc[0][3]);
            acc[1][0] = fmaf(a.y, b.x, acc[1][0]); acc[1][1] = fmaf(a.y, b.y, acc[1][1]);
            acc[1][2] = fmaf(a.y, b.z, acc[1][2]); acc[1][3] = fmaf(a.y, b.w, acc[1][3]);
            acc[2][0] = fmaf(a.z, b.x, acc[2][0]); acc[2][1] = fmaf(a.z, b.y, acc[2][1]);
            acc[2][2] = fmaf(a.z, b.z, acc[2][2]); acc[2][3] = fmaf(a.z, b.w, acc[2][3]);
            acc[3][0] = fmaf(a.w, b.x, acc[3][0]); acc[3][1] = fmaf(a.w, b.y, acc[3][1]);
            acc[3][2] = fmaf(a.w, b.z, acc[3][2]); acc[3][3] = fmaf(a.w, b.w, acc[3][3]);
        }
    }

    // epilogue: scale by dinv[r], store float4 per row
    int r0 = rb + ty * 4;
#pragma unroll
    for (int i = 0; i < 4; ++i) {
        int r = r0 + i;
        if (r < n) {
            float dv = dinv[r];
            float4 o;
            o.x = acc[i][0] * dv; o.y = acc[i][1] * dv;
            o.z = acc[i][2] * dv; o.w = acc[i][3] * dv;
            *reinterpret_cast<float4*>(&H[(size_t)r * OUT + co + tx * 4]) = o;
        }
    }
}

// One wave per node. Lanes split into EG = 64/(C/4) edge groups; each lane loads
// float4 of channels. Cross-group shfl_xor reduce at the end.
// out[d][:] = dinv[d] * (H[d][:] + sum_{s in in(d)} H[s][:]) + b[:]  (+ optional relu)
template <int C, bool RELU>
__global__ __launch_bounds__(256) void aggregate_kernel(const float* __restrict__ H,
                                                        const int* __restrict__ row,
                                                        const int* __restrict__ csr_src,
                                                        const float* __restrict__ dinv,
                                                        const float* __restrict__ bias,
                                                        float* __restrict__ Y, int n) {
    constexpr int LPN = C / 4;        // lanes covering one row: 8 / 16 / 32
    constexpr int EG = 64 / LPN;      // edge groups: 8 / 4 / 2
    int wid = (blockIdx.x * blockDim.x + threadIdx.x) >> 6;
    if (wid >= n) return;             // wave-uniform exit
    int lane = threadIdx.x & 63;
    int g = lane / LPN;
    int c0 = (lane % LPN) * 4;
    const int node = wid;

    float4 acc = make_float4(0.f, 0.f, 0.f, 0.f);
    if (g == 0) acc = *reinterpret_cast<const float4*>(H + (size_t)node * C + c0);  // self-loop
    int end = row[node + 1];
    for (int e = row[node] + g; e < end; e += EG) {
        int s = csr_src[e];
        float4 hv = *reinterpret_cast<const float4*>(H + (size_t)s * C + c0);
        acc.x += hv.x; acc.y += hv.y; acc.z += hv.z; acc.w += hv.w;
    }
#pragma unroll
    for (int m = LPN; m < 64; m <<= 1) {
        acc.x += __shfl_xor(acc.x, m);
        acc.y += __shfl_xor(acc.y, m);
        acc.z += __shfl_xor(acc.z, m);
        acc.w += __shfl_xor(acc.w, m);
    }
    if (g == 0) {
        float dv = dinv[node];
        float4 o;
        o.x = fmaf(acc.x, dv, bias[c0 + 0]);
        o.y = fmaf(acc.y, dv, bias[c0 + 1]);
        o.z = fmaf(acc.z, dv, bias[c0 + 2]);
        o.w = fmaf(acc.w, dv, bias[c0 + 3]);
        if (RELU) {
            o.x = fmaxf(o.x, 0.f); o.y = fmaxf(o.y, 0.f);
            o.z = fmaxf(o.z, 0.f); o.w = fmaxf(o.w, 0.f);
        }
        *reinterpret_cast<float4*>(Y + (size_t)node * C + c0) = o;
    }
}

// ---------------- host launch ----------------

static inline int cdiv(int a, int b) { return (a + b - 1) / b; }

extern "C" void kernel_launch(void* const* d_in, const int* in_sizes, int n_in,
                              void* d_out, int out_size, void* d_ws, size_t ws_size,
                              hipStream_t stream) {
    const float* x   = (const float*)d_in[0];
    const int*   ei  = (const int*)d_in[1];
    const float* We1 = (const float*)d_in[2];
    const float* be1 = (const float*)d_in[3];
    const float* We2 = (const float*)d_in[4];
    const float* be2 = (const float*)d_in[5];
    const float* Wd1 = (const float*)d_in[6];
    const float* bd1 = (const float*)d_in[7];
    const float* Wd2 = (const float*)d_in[8];
    const float* bd2 = (const float*)d_in[9];

    const int n = in_sizes[0] / 128;
    const int E = in_sizes[1] / 2;
    const int* src = ei;
    const int* dst = ei + E;
    const int nb = cdiv(n, SCAN_CHUNK);
    const int nrb = cdiv(n, 64);

    // carve workspace (256B aligned)
    char* ws = (char*)d_ws;
    auto carve = [&](size_t bytes) -> void* {
        void* p = (void*)ws;
        ws += (bytes + 255) & ~(size_t)255;
        return p;
    };
    int*   cnt  = (int*)carve((size_t)n * 4);
    int*   rowp = (int*)carve((size_t)(n + 1) * 4);
    int*   cur  = (int*)carve((size_t)n * 4);
    int*   csr  = (int*)carve((size_t)E * 4);
    float* dinv = (float*)carve((size_t)n * 4);
    int*   bsum = (int*)carve((size_t)nb * 4);
    float* bufA = (float*)carve((size_t)n * 128 * 4);
    float* bufB = (float*)carve((size_t)n * 64 * 4);
    float* bufC = (float*)carve((size_t)n * 32 * 4);

    // ---- graph preprocessing ----
    zero_int_kernel<<<cdiv(n, 256), 256, 0, stream>>>(cnt, n);
    count_edges_kernel<<<cdiv(E, 256), 256, 0, stream>>>(dst, E, cnt);
    block_sum_kernel<<<nb, 256, 0, stream>>>(cnt, n, bsum, dinv);
    local_scan_kernel<<<nb, 256, 0, stream>>>(cnt, n, bsum, rowp, cur);
    scatter_edges_kernel<<<cdiv(E, 256), 256, 0, stream>>>(src, dst, E, cur, csr);

    // ---- layer 1: 128 -> 64, relu ----
    gemm_tile_kernel<128, 64, 64><<<dim3(nrb, 1), 256, 0, stream>>>(x, We1, dinv, bufA, n);
    aggregate_kernel<64, true><<<cdiv(n * 64, 256), 256, 0, stream>>>(bufA, rowp, csr, dinv, be1, bufB, n);

    // ---- layer 2: 64 -> 32 ----
    gemm_tile_kernel<64, 32, 32><<<dim3(nrb, 1), 128, 0, stream>>>(bufB, We2, dinv, bufA, n);
    aggregate_kernel<32, false><<<cdiv(n * 64, 256), 256, 0, stream>>>(bufA, rowp, csr, dinv, be2, bufC, n);

    // ---- layer 3: 32 -> 64, relu ----
    gemm_tile_kernel<32, 64, 64><<<dim3(nrb, 1), 256, 0, stream>>>(bufC, Wd1, dinv, bufA, n);
    aggregate_kernel<64, true><<<cdiv(n * 64, 256), 256, 0, stream>>>(bufA, rowp, csr, dinv, bd1, bufB, n);

    // ---- layer 4: 64 -> 128 ----
    gemm_tile_kernel<64, 128, 64><<<dim3(nrb, 2), 256, 0, stream>>>(bufB, Wd2, dinv, bufA, n);
    aggregate_kernel<128, false><<<cdiv(n * 64, 256), 256, 0, stream>>>(bufA, rowp, csr, dinv, bd2, (float*)d_out, n);
}

// Round 4
// 262.159 us; speedup vs baseline: 2.4908x; 1.2012x over previous
//
#include <hip/hip_runtime.h>

// ---------------- graph preprocessing kernels ----------------

__global__ __launch_bounds__(256) void zero_int_kernel(int* __restrict__ p, int n) {
    int i = blockIdx.x * blockDim.x + threadIdx.x;
    if (i < n) p[i] = 0;
}

__global__ __launch_bounds__(256) void count_edges_kernel(const int* __restrict__ dst, int E,
                                                          int* __restrict__ cnt) {
    int e = blockIdx.x * blockDim.x + threadIdx.x;
    if (e < E) atomicAdd(&cnt[dst[e]], 1);
}

static constexpr int SCAN_CHUNK = 2048;   // per block: 256 threads x 8 elements

// per-block sum of cnt (+ dinv computed on the fly)
__global__ __launch_bounds__(256) void block_sum_kernel(const int* __restrict__ cnt, int n,
                                                        int* __restrict__ bsum,
                                                        float* __restrict__ dinv) {
    int tid = threadIdx.x;
    int base = blockIdx.x * SCAN_CHUNK;
    int lim = base + SCAN_CHUNK; if (lim > n) lim = n;
    int s = 0;
    for (int i = base + tid; i < lim; i += 256) {      // coalesced
        int c = cnt[i];
        s += c;
        dinv[i] = rsqrtf((float)(c + 1));              // +1 self-loop
    }
    __shared__ int red[4];
#pragma unroll
    for (int m = 1; m < 64; m <<= 1) s += __shfl_xor(s, m);
    int lane = tid & 63, w = tid >> 6;
    if (lane == 0) red[w] = s;
    __syncthreads();
    if (tid == 0) bsum[blockIdx.x] = red[0] + red[1] + red[2] + red[3];
}

// per-block exclusive scan with global offset; writes rowp and cur
__global__ __launch_bounds__(256) void local_scan_kernel(const int* __restrict__ cnt, int n,
                                                         const int* __restrict__ bsum,
                                                         int* __restrict__ rowp,
                                                         int* __restrict__ cur) {
    __shared__ int soff;
    __shared__ int wsum[4];
    int tid = threadIdx.x;
    int b = blockIdx.x;
    int lane = tid & 63, w = tid >> 6;
    if (tid < 64) {
        int v = 0;
        for (int i = tid; i < b; i += 64) v += bsum[i];
#pragma unroll
        for (int m = 1; m < 64; m <<= 1) v += __shfl_xor(v, m);
        if (tid == 0) soff = v;
    }
    int base = b * SCAN_CHUNK + tid * 8;
    int vals[8];
    int s = 0;
#pragma unroll
    for (int k = 0; k < 8; ++k) {
        int i = base + k;
        int c = (i < n) ? cnt[i] : 0;
        vals[k] = c;
        s += c;
    }
    // wave inclusive scan of s
    int inc = s;
#pragma unroll
    for (int m = 1; m < 64; m <<= 1) {
        int u = __shfl_up(inc, m);
        if (lane >= m) inc += u;
    }
    if (lane == 63) wsum[w] = inc;
    __syncthreads();
    int off = soff;
    for (int i = 0; i < w; ++i) off += wsum[i];
    int run = off + inc - s;                 // exclusive prefix for this thread's 8 elems
#pragma unroll
    for (int k = 0; k < 8; ++k) {
        int i = base + k;
        if (i < n) { rowp[i] = run; cur[i] = run; }
        run += vals[k];
    }
    if (b == (int)gridDim.x - 1 && tid == 255) rowp[n] = run;  // == E
}

__global__ __launch_bounds__(256) void scatter_edges_kernel(const int* __restrict__ src,
                                                            const int* __restrict__ dst, int E,
                                                            int* __restrict__ cur,
                                                            int* __restrict__ csr_src) {
    int e = blockIdx.x * blockDim.x + threadIdx.x;
    if (e < E) {
        int d = dst[e];
        int pos = atomicAdd(&cur[d], 1);
        csr_src[pos] = src[e];
    }
}

// ---------------- per-layer kernels ----------------

// Block-tiled GEMM: H[r][c] = epi(sum_k X[r][k] W[k][c])
// epi: +bias (BIAS), relu (RELU), * dinv[r] (SCALE) — in that order.
template <int K, int OUT, int BN, bool BIAS, bool RELU, bool SCALE>
__global__ __launch_bounds__(16 * (BN / 4)) void gemm_tile_kernel(
        const float* __restrict__ X, const float* __restrict__ W,
        const float* __restrict__ bias, const float* __restrict__ dinv,
        float* __restrict__ H, int n) {
    constexpr int BM = 64;
    constexpr int KB = (K > 64) ? 64 : K;
    constexpr int NTHR = 16 * (BN / 4);
    constexpr int KV = KB / 4;              // float4s per A row chunk

    __shared__ float At[KB][BM + 4];        // [k][r], stride 68 floats
    __shared__ float Bl[K][BN];

    const int tid = threadIdx.x;
    const int tx = tid % (BN / 4);
    const int ty = tid / (BN / 4);
    const int rb = blockIdx.x * BM;
    const int co = blockIdx.y * BN;

    // load B panel (W[:, co:co+BN]) once
    for (int i = tid; i < K * BN / 4; i += NTHR) {
        int k = i / (BN / 4);
        int c0 = (i % (BN / 4)) * 4;
        *reinterpret_cast<float4*>(&Bl[k][c0]) =
            *reinterpret_cast<const float4*>(&W[(size_t)k * OUT + co + c0]);
    }

    float acc[4][4] = {};

#pragma unroll
    for (int ch = 0; ch < K / KB; ++ch) {
        if (ch) __syncthreads();            // previous chunk's readers done
        // stage A chunk transposed
        for (int i = tid; i < BM * KV; i += NTHR) {
            int r = i / KV;
            int k0 = (i % KV) * 4;
            int rg = rb + r; if (rg > n - 1) rg = n - 1;     // clamp tail
            float4 xv = *reinterpret_cast<const float4*>(&X[(size_t)rg * K + ch * KB + k0]);
            At[k0 + 0][r] = xv.x;
            At[k0 + 1][r] = xv.y;
            At[k0 + 2][r] = xv.z;
            At[k0 + 3][r] = xv.w;
        }
        __syncthreads();

#pragma unroll 8
        for (int k = 0; k < KB; ++k) {
            float4 a = *reinterpret_cast<const float4*>(&At[k][ty * 4]);
            float4 b = *reinterpret_cast<const float4*>(&Bl[ch * KB + k][tx * 4]);
            acc[0][0] = fmaf(a.x, b.x, acc[0][0]); acc[0][1] = fmaf(a.x, b.y, acc[0][1]);
            acc[0][2] = fmaf(a.x, b.z, acc[0][2]); acc[0][3] = fmaf(a.x, b.w, acc[0][3]);
            acc[1][0] = fmaf(a.y, b.x, acc[1][0]); acc[1][1] = fmaf(a.y, b.y, acc[1][1]);
            acc[1][2] = fmaf(a.y, b.z, acc[1][2]); acc[1][3] = fmaf(a.y, b.w, acc[1][3]);
            acc[2][0] = fmaf(a.z, b.x, acc[2][0]); acc[2][1] = fmaf(a.z, b.y, acc[2][1]);
            acc[2][2] = fmaf(a.z, b.z, acc[2][2]); acc[2][3] = fmaf(a.z, b.w, acc[2][3]);
            acc[3][0] = fmaf(a.w, b.x, acc[3][0]); acc[3][1] = fmaf(a.w, b.y, acc[3][1]);
            acc[3][2] = fmaf(a.w, b.z, acc[3][2]); acc[3][3] = fmaf(a.w, b.w, acc[3][3]);
        }
    }

    float4 bv = make_float4(0.f, 0.f, 0.f, 0.f);
    if (BIAS) bv = *reinterpret_cast<const float4*>(&bias[co + tx * 4]);
    int r0 = rb + ty * 4;
#pragma unroll
    for (int i = 0; i < 4; ++i) {
        int r = r0 + i;
        if (r < n) {
            float4 o;
            o.x = acc[i][0]; o.y = acc[i][1]; o.z = acc[i][2]; o.w = acc[i][3];
            if (BIAS) { o.x += bv.x; o.y += bv.y; o.z += bv.z; o.w += bv.w; }
            if (RELU) {
                o.x = fmaxf(o.x, 0.f); o.y = fmaxf(o.y, 0.f);
                o.z = fmaxf(o.z, 0.f); o.w = fmaxf(o.w, 0.f);
            }
            if (SCALE) {
                float dv = dinv[r];
                o.x *= dv; o.y *= dv; o.z *= dv; o.w *= dv;
            }
            *reinterpret_cast<float4*>(&H[(size_t)r * OUT + co + tx * 4]) = o;
        }
    }
}

// One wave per node. Lanes split into EG = 64/(C/4) edge groups; each lane loads
// float4 of channels; 2x-unrolled edge loop for MLP. Cross-group shfl_xor reduce.
// o = dinv[d]*(H[d]+sum H[s]); if BIAS o += b; if RELU relu; if POST o *= dinv[d].
template <int C, bool RELU, bool HAS_BIAS, bool POST_SCALE>
__global__ __launch_bounds__(256) void aggregate_kernel(const float* __restrict__ H,
                                                        const int* __restrict__ row,
                                                        const int* __restrict__ csr_src,
                                                        const float* __restrict__ dinv,
                                                        const float* __restrict__ bias,
                                                        float* __restrict__ Y, int n) {
    constexpr int LPN = C / 4;        // lanes covering one row: 8 / 16
    constexpr int EG = 64 / LPN;      // edge groups: 8 / 4
    int wid = (blockIdx.x * blockDim.x + threadIdx.x) >> 6;
    if (wid >= n) return;             // wave-uniform exit
    int lane = threadIdx.x & 63;
    int g = lane / LPN;
    int c0 = (lane % LPN) * 4;
    const int node = wid;

    float4 acc = make_float4(0.f, 0.f, 0.f, 0.f);
    float4 acc2 = make_float4(0.f, 0.f, 0.f, 0.f);
    if (g == 0) acc = *reinterpret_cast<const float4*>(H + (size_t)node * C + c0);  // self-loop
    int e = row[node] + g;
    int end = row[node + 1];
    for (; e + EG < end; e += 2 * EG) {
        int s1 = csr_src[e];
        int s2 = csr_src[e + EG];
        float4 h1 = *reinterpret_cast<const float4*>(H + (size_t)s1 * C + c0);
        float4 h2 = *reinterpret_cast<const float4*>(H + (size_t)s2 * C + c0);
        acc.x += h1.x; acc.y += h1.y; acc.z += h1.z; acc.w += h1.w;
        acc2.x += h2.x; acc2.y += h2.y; acc2.z += h2.z; acc2.w += h2.w;
    }
    if (e < end) {
        int s = csr_src[e];
        float4 hv = *reinterpret_cast<const float4*>(H + (size_t)s * C + c0);
        acc.x += hv.x; acc.y += hv.y; acc.z += hv.z; acc.w += hv.w;
    }
    acc.x += acc2.x; acc.y += acc2.y; acc.z += acc2.z; acc.w += acc2.w;
#pragma unroll
    for (int m = LPN; m < 64; m <<= 1) {
        acc.x += __shfl_xor(acc.x, m);
        acc.y += __shfl_xor(acc.y, m);
        acc.z += __shfl_xor(acc.z, m);
        acc.w += __shfl_xor(acc.w, m);
    }
    if (g == 0) {
        float dv = dinv[node];
        float4 o;
        o.x = acc.x * dv; o.y = acc.y * dv; o.z = acc.z * dv; o.w = acc.w * dv;
        if (HAS_BIAS) {
            o.x += bias[c0 + 0]; o.y += bias[c0 + 1];
            o.z += bias[c0 + 2]; o.w += bias[c0 + 3];
        }
        if (RELU) {
            o.x = fmaxf(o.x, 0.f); o.y = fmaxf(o.y, 0.f);
            o.z = fmaxf(o.z, 0.f); o.w = fmaxf(o.w, 0.f);
        }
        if (POST_SCALE) { o.x *= dv; o.y *= dv; o.z *= dv; o.w *= dv; }
        *reinterpret_cast<float4*>(Y + (size_t)node * C + c0) = o;
    }
}

// ---------------- host launch ----------------

static inline int cdiv(int a, int b) { return (a + b - 1) / b; }

extern "C" void kernel_launch(void* const* d_in, const int* in_sizes, int n_in,
                              void* d_out, int out_size, void* d_ws, size_t ws_size,
                              hipStream_t stream) {
    const float* x   = (const float*)d_in[0];
    const int*   ei  = (const int*)d_in[1];
    const float* We1 = (const float*)d_in[2];
    const float* be1 = (const float*)d_in[3];
    const float* We2 = (const float*)d_in[4];
    const float* be2 = (const float*)d_in[5];
    const float* Wd1 = (const float*)d_in[6];
    const float* bd1 = (const float*)d_in[7];
    const float* Wd2 = (const float*)d_in[8];
    const float* bd2 = (const float*)d_in[9];

    const int n = in_sizes[0] / 128;
    const int E = in_sizes[1] / 2;
    const int* src = ei;
    const int* dst = ei + E;
    const int nb = cdiv(n, SCAN_CHUNK);
    const int nrb = cdiv(n, 64);
    const int nwv = cdiv(n * 64, 256);      // one wave per node

    // carve workspace (256B aligned)
    char* ws = (char*)d_ws;
    auto carve = [&](size_t bytes) -> void* {
        void* p = (void*)ws;
        ws += (bytes + 255) & ~(size_t)255;
        return p;
    };
    int*   cnt  = (int*)carve((size_t)n * 4);
    int*   rowp = (int*)carve((size_t)(n + 1) * 4);
    int*   cur  = (int*)carve((size_t)n * 4);
    int*   csr  = (int*)carve((size_t)E * 4);
    float* dinv = (float*)carve((size_t)n * 4);
    int*   bsum = (int*)carve((size_t)nb * 4);
    float* bufA = (float*)carve((size_t)n * 64 * 4);
    float* bufB = (float*)carve((size_t)n * 64 * 4);
    float* bufC = (float*)carve((size_t)n * 32 * 4);

    // ---- graph preprocessing ----
    zero_int_kernel<<<cdiv(n, 256), 256, 0, stream>>>(cnt, n);
    count_edges_kernel<<<cdiv(E, 256), 256, 0, stream>>>(dst, E, cnt);
    block_sum_kernel<<<nb, 256, 0, stream>>>(cnt, n, bsum, dinv);
    local_scan_kernel<<<nb, 256, 0, stream>>>(cnt, n, bsum, rowp, cur);
    scatter_edges_kernel<<<cdiv(E, 256), 256, 0, stream>>>(src, dst, E, cur, csr);

    // ---- layer 1: 128 -> 64 (GEMM then aggregate), relu ----
    // H1s = dinv ⊙ (X We1);  B1 = relu(dinv ⊙ agg(H1s) + b)
    gemm_tile_kernel<128, 64, 64, false, false, true>
        <<<dim3(nrb, 1), 256, 0, stream>>>(x, We1, nullptr, dinv, bufA, n);
    aggregate_kernel<64, true, true, false>
        <<<nwv, 256, 0, stream>>>(bufA, rowp, csr, dinv, be1, bufB, n);

    // ---- layer 2: 64 -> 32 (GEMM then aggregate); output pre-scaled for L3 ----
    // H2s = dinv ⊙ (B1 We2);  Zs = dinv ⊙ (dinv ⊙ agg(H2s) + b)
    gemm_tile_kernel<64, 32, 32, false, false, true>
        <<<dim3(nrb, 1), 128, 0, stream>>>(bufB, We2, nullptr, dinv, bufA, n);
    aggregate_kernel<32, false, true, true>
        <<<nwv, 256, 0, stream>>>(bufA, rowp, csr, dinv, be2, bufC, n);

    // ---- layer 3: 32 -> 64 (aggregate FIRST, then GEMM), relu; pre-scaled for L4 ----
    // A3 = dinv ⊙ agg(Zs)  (= S·Z);  Ds = dinv ⊙ relu(A3 Wd1 + b)
    aggregate_kernel<32, false, false, false>
        <<<nwv, 256, 0, stream>>>(bufC, rowp, csr, dinv, nullptr, bufA, n);
    gemm_tile_kernel<32, 64, 64, true, true, true>
        <<<dim3(nrb, 1), 256, 0, stream>>>(bufA, Wd1, bd1, dinv, bufB, n);

    // ---- layer 4: 64 -> 128 (aggregate FIRST, then GEMM) ----
    // A4 = dinv ⊙ agg(Ds)  (= S·D);  out = A4 Wd2 + b
    aggregate_kernel<64, false, false, false>
        <<<nwv, 256, 0, stream>>>(bufB, rowp, csr, dinv, nullptr, bufA, n);
    gemm_tile_kernel<64, 128, 64, true, false, false>
        <<<dim3(nrb, 2), 256, 0, stream>>>(bufA, Wd2, bd2, dinv, (float*)d_out, n);
}